// Round 2
// baseline (1773.187 us; speedup 1.0000x reference)
//
#include <hip/hip_runtime.h>
#include <stdint.h>
#include <math.h>

// PendulumHJBLoss: 3 MLP passes (2->128->128->2, tanh) over N=524288 + losses.
// R20: recovery from R19's spill disaster (launch_bounds(1024,8) -> 32 arch
// VGPRs -> 1.4GB scratch writes). Keeps R19's verified flipped-MFMA epilogue
// (mfma(Bv,Av) computes C2^T[hidout][elem]; layer-3 partials lane-local,
// 2-step qred, no select chains). NEW: direct layer-1 -- with the flipped
// layout a lane's h1 fragment is h1[elem=l15][hid=32s+8q+j], hid depends only
// on quad, so each lane computes its own fragment from its own (p,q) with
// quad-uniform W1/b1 LDS broadcast reads. Deletes the 70KB staging buffer,
// all transposes, all __shfl broadcasts, all wave barriers in the hot loop.
// Config: 512-thr blocks, __launch_bounds__(512,4) -> 128-VGPR cap (no spill),
// 2 blocks/CU by LDS (~152KB), 16 waves/CU (register-capped ceiling).
// B-frags in LDS (known good); symplectic rows + ticket finalize unchanged.

constexpr float EPS_FD = 1e-4f;
constexpr float K2LOG2E = 2.8853900817779268f;   // 2*log2(e)

typedef float f32x4 __attribute__((ext_vector_type(4)));
typedef short s16x8 __attribute__((ext_vector_type(8)));

// tanh with pre-scaled input: expects x_pre = 2*log2(e) * x
__device__ __forceinline__ float tanh_pre(float x) {
  float e = __builtin_amdgcn_exp2f(x);
  return 1.0f - 2.0f * __builtin_amdgcn_rcpf(e + 1.0f);
}
__device__ __forceinline__ float cos_fast(float x) {
  return __builtin_amdgcn_cosf(x * 0.15915494309189535f);
}
__device__ __forceinline__ unsigned bf16rne(float f) {
  union { float f; unsigned u; } v; v.f = f;
  return (v.u + 0x7FFFu + ((v.u >> 16) & 1u)) >> 16;
}
__device__ __forceinline__ unsigned pack2rne(float a, float b) {
  return bf16rne(a) | (bf16rne(b) << 16);
}
// two fp32 -> packed bf16 pair (round-half-up) with one v_perm
__device__ __forceinline__ unsigned packbf(float lo, float hi) {
  union { float f; unsigned u; } a, b; a.f = lo; b.f = hi;
  return __builtin_amdgcn_perm(b.u + 0x8000u, a.u + 0x8000u, 0x07060302u);
}
// cross-quad reduce (same l15 column): full sum lands on ALL lanes
__device__ __forceinline__ float qred(float v) {
  v += __shfl_xor(v, 16, 64);
  v += __shfl_xor(v, 32, 64);
  return v;
}

// ---------------------------------------------------------------------------
// Direct layer-1 for TWO inputs sharing weight reads. Lane produces the
// h1^T B-frag directly: frag s holds h1[elem=l15][hid=32s+8q+j], j=0..7,
// bf16 pairs (2j,2j+1). W layout in LDS: [0..127]=K*W1[0][h], [128..255]=
// K*W1[1][h], [256..383]=K*b1[h]. Reads are quad-uniform (broadcast).
// ---------------------------------------------------------------------------
__device__ __forceinline__ void layer1_two(
    float pa, float qa, float pb, float qb,
    const float* W, int h0base, s16x8 (&A)[4], s16x8 (&B)[4])
{
#pragma unroll
  for (int s = 0; s < 4; s++) {
    int h0 = 32 * s + h0base;
    f32x4 wp0 = *reinterpret_cast<const f32x4*>(&W[h0]);
    f32x4 wp1 = *reinterpret_cast<const f32x4*>(&W[h0 + 4]);
    f32x4 wq0 = *reinterpret_cast<const f32x4*>(&W[128 + h0]);
    f32x4 wq1 = *reinterpret_cast<const f32x4*>(&W[128 + h0 + 4]);
    f32x4 bb0 = *reinterpret_cast<const f32x4*>(&W[256 + h0]);
    f32x4 bb1 = *reinterpret_cast<const f32x4*>(&W[256 + h0 + 4]);
    union { unsigned u[4]; s16x8 v; } ua, ub;
#pragma unroll
    for (int c = 0; c < 2; c++) {
      f32x4 wp = c ? wp1 : wp0;
      f32x4 wq = c ? wq1 : wq0;
      f32x4 bv = c ? bb1 : bb0;
      float a0 = tanh_pre(fmaf(pa, wp[0], fmaf(qa, wq[0], bv[0])));
      float a1 = tanh_pre(fmaf(pa, wp[1], fmaf(qa, wq[1], bv[1])));
      float a2 = tanh_pre(fmaf(pa, wp[2], fmaf(qa, wq[2], bv[2])));
      float a3 = tanh_pre(fmaf(pa, wp[3], fmaf(qa, wq[3], bv[3])));
      ua.u[2 * c]     = packbf(a0, a1);
      ua.u[2 * c + 1] = packbf(a2, a3);
      float e0 = tanh_pre(fmaf(pb, wp[0], fmaf(qb, wq[0], bv[0])));
      float e1 = tanh_pre(fmaf(pb, wp[1], fmaf(qb, wq[1], bv[1])));
      float e2 = tanh_pre(fmaf(pb, wp[2], fmaf(qb, wq[2], bv[2])));
      float e3 = tanh_pre(fmaf(pb, wp[3], fmaf(qb, wq[3], bv[3])));
      ub.u[2 * c]     = packbf(e0, e1);
      ub.u[2 * c + 1] = packbf(e2, e3);
    }
    A[s] = ua.v; B[s] = ub.v;
  }
}

__device__ __forceinline__ void layer1_one(
    float pa, float qa, const float* W, int h0base, s16x8 (&A)[4])
{
#pragma unroll
  for (int s = 0; s < 4; s++) {
    int h0 = 32 * s + h0base;
    f32x4 wp0 = *reinterpret_cast<const f32x4*>(&W[h0]);
    f32x4 wp1 = *reinterpret_cast<const f32x4*>(&W[h0 + 4]);
    f32x4 wq0 = *reinterpret_cast<const f32x4*>(&W[128 + h0]);
    f32x4 wq1 = *reinterpret_cast<const f32x4*>(&W[128 + h0 + 4]);
    f32x4 bb0 = *reinterpret_cast<const f32x4*>(&W[256 + h0]);
    f32x4 bb1 = *reinterpret_cast<const f32x4*>(&W[256 + h0 + 4]);
    union { unsigned u[4]; s16x8 v; } ua;
#pragma unroll
    for (int c = 0; c < 2; c++) {
      f32x4 wp = c ? wp1 : wp0;
      f32x4 wq = c ? wq1 : wq0;
      f32x4 bv = c ? bb1 : bb0;
      float a0 = tanh_pre(fmaf(pa, wp[0], fmaf(qa, wq[0], bv[0])));
      float a1 = tanh_pre(fmaf(pa, wp[1], fmaf(qa, wq[1], bv[1])));
      float a2 = tanh_pre(fmaf(pa, wp[2], fmaf(qa, wq[2], bv[2])));
      float a3 = tanh_pre(fmaf(pa, wp[3], fmaf(qa, wq[3], bv[3])));
      ua.u[2 * c]     = packbf(a0, a1);
      ua.u[2 * c + 1] = packbf(a2, a3);
    }
    A[s] = ua.v;
  }
}

// ---------------------------------------------------------------------------
// Dual encoder pass (flipped): C2^T[hidout=16t+4q+r][elem=l15]; layer-3
// accumulates per-lane scalars; cross-quad qred finishes. Outputs on ALL
// lanes (elem = l15).
// epi: [0..127]=K*b2[hid]; [128+2*hid]=W3[hid][0]; [128+2*hid+1]=W3[hid][1]
// ---------------------------------------------------------------------------
__device__ __forceinline__ void enc_pair(
    float p0e, float q0e, float p1e, float q1e,
    const float* W, const uint4* Bf, const float* epi,
    int lane, int quad, int l15,
    float& P0v, float& Q0v, float& P1v, float& Q1v)
{
  s16x8 A0[4], A1[4];
  layer1_two(p0e, q0e, p1e, q1e, W, 8 * quad, A0, A1);

  float sP0 = 0.f, sQ0 = 0.f, sP1 = 0.f, sQ1 = 0.f;
#pragma unroll
  for (int t = 0; t < 8; t++) {
    f32x4 acc0 = *reinterpret_cast<const f32x4*>(&epi[16 * t + 4 * quad]);
    f32x4 acc1 = acc0;
#pragma unroll
    for (int s = 0; s < 4; s++) {
      uint4 bu = Bf[(s * 8 + t) * 64 + lane];     // ONE read, TWO MFMAs
      s16x8 Bv = *reinterpret_cast<s16x8*>(&bu);
      acc0 = __builtin_amdgcn_mfma_f32_16x16x32_bf16(Bv, A0[s], acc0, 0, 0, 0);
      acc1 = __builtin_amdgcn_mfma_f32_16x16x32_bf16(Bv, A1[s], acc1, 0, 0, 0);
    }
    f32x4 w3a = *reinterpret_cast<const f32x4*>(&epi[128 + 32 * t + 8 * quad]);
    f32x4 w3b = *reinterpret_cast<const f32x4*>(&epi[128 + 32 * t + 8 * quad + 4]);
#pragma unroll
    for (int r = 0; r < 4; r++) {
      float wP = (r == 0) ? w3a[0] : (r == 1) ? w3a[2] : (r == 2) ? w3b[0] : w3b[2];
      float wQ = (r == 0) ? w3a[1] : (r == 1) ? w3a[3] : (r == 2) ? w3b[1] : w3b[3];
      float h0 = tanh_pre(acc0[r]);
      float h1 = tanh_pre(acc1[r]);
      sP0 = fmaf(h0, wP, sP0); sQ0 = fmaf(h0, wQ, sQ0);
      sP1 = fmaf(h1, wP, sP1); sQ1 = fmaf(h1, wQ, sQ1);
    }
  }
  P0v = qred(sP0); Q0v = qred(sQ0);
  P1v = qred(sP1); Q1v = qred(sQ1);
}

__device__ __forceinline__ void dec_pass(
    float pe, float qe,
    const float* W, const uint4* Bf, const float* epi,
    int lane, int quad, int l15, float& vP, float& vQ)
{
  s16x8 A[4];
  layer1_one(pe, qe, W, 8 * quad, A);
  float sP = 0.f, sQ = 0.f;
#pragma unroll
  for (int t = 0; t < 8; t++) {
    f32x4 acc = *reinterpret_cast<const f32x4*>(&epi[16 * t + 4 * quad]);
#pragma unroll
    for (int s = 0; s < 4; s++) {
      uint4 bu = Bf[(s * 8 + t) * 64 + lane];
      s16x8 Bv = *reinterpret_cast<s16x8*>(&bu);
      acc = __builtin_amdgcn_mfma_f32_16x16x32_bf16(Bv, A[s], acc, 0, 0, 0);
    }
    f32x4 w3a = *reinterpret_cast<const f32x4*>(&epi[128 + 32 * t + 8 * quad]);
    f32x4 w3b = *reinterpret_cast<const f32x4*>(&epi[128 + 32 * t + 8 * quad + 4]);
#pragma unroll
    for (int r = 0; r < 4; r++) {
      float wP = (r == 0) ? w3a[0] : (r == 1) ? w3a[2] : (r == 2) ? w3b[0] : w3b[2];
      float wQ = (r == 0) ? w3a[1] : (r == 1) ? w3a[3] : (r == 2) ? w3b[1] : w3b[3];
      float h = tanh_pre(acc[r]);
      sP = fmaf(h, wP, sP);
      sQ = fmaf(h, wQ, sQ);
    }
  }
  vP = qred(sP); vQ = qred(sQ);
}

// ---------------------------------------------------------------------------
// Main persistent kernel: 512 threads (8 waves), 2 blocks/CU by LDS,
// 128-VGPR cap via launch_bounds(512,4).
// ---------------------------------------------------------------------------
__global__ __launch_bounds__(512, 4) void mlp_main(
    const float* __restrict__ p0, const float* __restrict__ q0,
    const float* __restrict__ p1, const float* __restrict__ q1,
    const float* __restrict__ eW1, const float* __restrict__ eb1,
    const float* __restrict__ eW2, const float* __restrict__ eb2,
    const float* __restrict__ eW3, const float* __restrict__ eb3,
    const float* __restrict__ dW1, const float* __restrict__ db1,
    const float* __restrict__ dW2, const float* __restrict__ db2,
    const float* __restrict__ dW3, const float* __restrict__ db3,
    const float* __restrict__ omega, const float* __restrict__ Pt,
    const float* __restrict__ Qt, const float* __restrict__ dtp,
    float* __restrict__ acc5, unsigned* __restrict__ counter,
    float* __restrict__ PQ, float* __restrict__ out, int n)
{
  __shared__ uint4 BfL[4096];       // [0..2047]=enc frags, [2048..]=dec frags
  __shared__ float WE[384];         // enc K*W1p | K*W1q | K*b1
  __shared__ float WD[384];         // dec same
  __shared__ float encEpi[384];     // K*b2[128] | W3 interleaved[256]
  __shared__ float decEpi[384];
  __shared__ float symp[8][132];    // per-wave fp32 h1 scratch (symplectic)
  __shared__ float red[8][5];
  __shared__ unsigned lastflag;

  int tid = threadIdx.x;
  // B-frag staging: frag f=s*8+t; lane L holds W2[k=32s+8(L>>4)+j][col=16t+(L&15)]
  {
    unsigned* BE = (unsigned*)&BfL[0];
    unsigned* BD = (unsigned*)&BfL[2048];
#pragma unroll
    for (int it = 0; it < 16; it++) {
      int id = tid + it * 512;                // u32 entry 0..8191
      int jj = id & 3, ln = (id >> 2) & 63, f = id >> 8;
      int s = f >> 3, t = f & 7;
      int k   = 32 * s + 8 * (ln >> 4) + 2 * jj;
      int col = 16 * t + (ln & 15);
      BE[id] = pack2rne(eW2[k * 128 + col] * K2LOG2E,
                        eW2[(k + 1) * 128 + col] * K2LOG2E);
      BD[id] = pack2rne(dW2[k * 128 + col] * K2LOG2E,
                        dW2[(k + 1) * 128 + col] * K2LOG2E);
    }
  }
  if (tid < 256) {                   // eW1 is (2,128) row-major
    WE[tid] = eW1[tid] * K2LOG2E;
    WD[tid] = dW1[tid] * K2LOG2E;
    encEpi[128 + tid] = eW3[tid];
    decEpi[128 + tid] = dW3[tid];
  } else if (tid < 384) {
    int u = tid - 256;
    WE[256 + u] = eb1[u] * K2LOG2E;
    WD[256 + u] = db1[u] * K2LOG2E;
  } else {
    int u = tid - 384;
    encEpi[u] = eb2[u] * K2LOG2E;
    decEpi[u] = db2[u] * K2LOG2E;
  }

  int wave = tid >> 6, lane = tid & 63;
  int quad = lane >> 4, l15 = lane & 15;

  float eb3P = eb3[0], eb3Q = eb3[1];
  float db3P = db3[0], db3Q = db3[1];
  float dt = dtp[0];
  float s0 = 0.f, s1 = 0.f, s2 = 0.f, s3 = 0.f, s4 = 0.f;
  __syncthreads();   // LDS staging done; the only block barrier before tail

  int nwaves = gridDim.x * 8;
  int gwave  = blockIdx.x * 8 + wave;
  int ntiles = (n + 15) >> 4;

  // ---- fused exact-fp32 symplectic rows: one per wave for gwave < 128 ----
  // (reads RAW weights from global; unaffected by pre-scaling)
  if (gwave < 128) {
    int r = gwave;
    int m = r & 31, c = r >> 5;           // c: 0=p+e 1=p-e 2=q+e 3=q-e
    float p = p0[m], q = q0[m];
    p += (c == 0) ? EPS_FD : (c == 1) ? -EPS_FD : 0.f;
    q += (c == 2) ? EPS_FD : (c == 3) ? -EPS_FD : 0.f;
    float* hf = &symp[wave][0];
    int t0 = 2 * lane, t1 = 2 * lane + 1;
    float h0 = tanhf(fmaf(p, eW1[t0], fmaf(q, eW1[128 + t0], eb1[t0])));
    float h1v = tanhf(fmaf(p, eW1[t1], fmaf(q, eW1[128 + t1], eb1[t1])));
    hf[t0] = h0; hf[t1] = h1v;
    __builtin_amdgcn_wave_barrier();
    float a0 = eb2[t0], a1 = eb2[t1];
#pragma unroll 8
    for (int k = 0; k < 128; k++) {
      float hk = hf[k];                   // LDS broadcast (same addr all lanes)
      a0 = fmaf(hk, eW2[k * 128 + t0], a0);
      a1 = fmaf(hk, eW2[k * 128 + t1], a1);
    }
    float g0 = tanhf(a0), g1 = tanhf(a1);
    float cP = fmaf(g0, eW3[2 * t0],     g1 * eW3[2 * t1]);
    float cQ = fmaf(g0, eW3[2 * t0 + 1], g1 * eW3[2 * t1 + 1]);
#pragma unroll
    for (int mm = 1; mm < 64; mm <<= 1) {
      cP += __shfl_xor(cP, mm, 64);
      cQ += __shfl_xor(cQ, mm, 64);
    }
    if (lane == 0) {
      atomicExch(&PQ[2 * r],     cP + eb3P);   // device-scope publish
      atomicExch(&PQ[2 * r + 1], cQ + eb3Q);
    }
  }

  const uint4* BfE = &BfL[0];
  const uint4* BfD = &BfL[2048];

  for (int tile = gwave; tile < ntiles; tile += nwaves) {
    int base = tile * 16;
    int e = base + l15; if (e >= n) e = n - 1;
    float p0e = p0[e], q0e = q0[e];
    float p1e = p1[e], q1e = q1[e];
    float Lom = omega[e], LPt = Pt[e], LQt = Qt[e];

    float P0v, Q0v, P1v, Q1v, RPv, RQv;
    enc_pair(p0e, q0e, p1e, q1e, WE, BfE, encEpi,
             lane, quad, l15, P0v, Q0v, P1v, Q1v);
    P0v += eb3P; Q0v += eb3Q;
    P1v += eb3P; Q1v += eb3Q;
    dec_pass(P0v, Q0v, WD, BfD, decEpi,
             lane, quad, l15, RPv, RQv);
    RPv += db3P; RQv += db3Q;

    if (quad == 0 && base + l15 < n) {
      float dp = p0e - RPv, dq = q0e - RQv;
      s0 += dp * dp + dq * dq;                       // recon
      float d1 = P0v - P1v; s1 += d1 * d1;           // conservation
      s2 += 1.0f - cos_fast(Q1v - Q0v - Lom * dt);   // evolution
      float g = P0v - LPt; s3 += g * g;              // gauge P
      s4 += 1.0f - cos_fast(Q0v - LQt);              // gauge Q
    }
  }

  // block reduction -> global atomics -> ticket -> last block finalizes
#pragma unroll
  for (int m = 1; m < 64; m <<= 1) {
    s0 += __shfl_xor(s0, m, 64);
    s1 += __shfl_xor(s1, m, 64);
    s2 += __shfl_xor(s2, m, 64);
    s3 += __shfl_xor(s3, m, 64);
    s4 += __shfl_xor(s4, m, 64);
  }
  if (lane == 0) {
    red[wave][0] = s0; red[wave][1] = s1; red[wave][2] = s2;
    red[wave][3] = s3; red[wave][4] = s4;
  }
  __syncthreads();
  if (tid == 0) {
#pragma unroll
    for (int i = 0; i < 5; i++) {
      float v = 0.f;
#pragma unroll
      for (int w = 0; w < 8; w++) v += red[w][i];
      atomicAdd(&acc5[i], v);
    }
    __threadfence();
    unsigned prev = atomicAdd(counter, 1u);
    lastflag = (prev == gridDim.x - 1) ? 1u : 0u;
  }
  __syncthreads();
  if (lastflag) {
    __threadfence();
    if (tid < 64) {
      float v = 0.f;
      if (tid < 32) {
        // PQ read through device-scope atomics (cross-XCD safe)
        float Ppp = atomicAdd(&PQ[2 * tid], 0.f);
        float Qpp = atomicAdd(&PQ[2 * tid + 1], 0.f);
        float Ppm = atomicAdd(&PQ[2 * (32 + tid)], 0.f);
        float Qpm = atomicAdd(&PQ[2 * (32 + tid) + 1], 0.f);
        float Pqp = atomicAdd(&PQ[2 * (64 + tid)], 0.f);
        float Qqp = atomicAdd(&PQ[2 * (64 + tid) + 1], 0.f);
        float Pqm = atomicAdd(&PQ[2 * (96 + tid)], 0.f);
        float Qqm = atomicAdd(&PQ[2 * (96 + tid) + 1], 0.f);
        float inv2e = 1.0f / (2.0f * EPS_FD);
        float dPdp = (Ppp - Ppm) * inv2e, dPdq = (Pqp - Pqm) * inv2e;
        float dQdp = (Qpp - Qpm) * inv2e, dQdq = (Qqp - Qqm) * inv2e;
        float pb = dPdq * dQdp - dPdp * dQdq;
        float d = fabsf(pb) - 1.0f;
        v = d * d;
      }
#pragma unroll
      for (int m = 1; m < 64; m <<= 1) v += __shfl_xor(v, m, 64);
      if (tid == 0) {
        float inv_n = 1.0f / (float)n;
        float recon = atomicAdd(&acc5[0], 0.f) * inv_n;
        float cons  = atomicAdd(&acc5[1], 0.f) * inv_n;
        float evo   = atomicAdd(&acc5[2], 0.f) * inv_n;
        float gauge = (atomicAdd(&acc5[3], 0.f) + atomicAdd(&acc5[4], 0.f)) * inv_n;
        float symp_  = v * (1.0f / 32.0f);
        float total = recon + 10.0f * cons + 5.0f * evo + 0.1f * symp_ + 5.0f * gauge;
        out[0] = total; out[1] = recon; out[2] = cons;
        out[3] = evo;   out[4] = symp_; out[5] = gauge;
      }
    }
  }
}

extern "C" void kernel_launch(void* const* d_in, const int* in_sizes, int n_in,
                              void* d_out, int out_size, void* d_ws, size_t ws_size,
                              hipStream_t stream)
{
  const float* p0    = (const float*)d_in[0];
  const float* q0    = (const float*)d_in[1];
  const float* p1    = (const float*)d_in[2];
  const float* q1    = (const float*)d_in[3];
  const float* omega = (const float*)d_in[4];
  const float* dtp   = (const float*)d_in[5];
  const float* Pt    = (const float*)d_in[6];
  const float* Qt    = (const float*)d_in[7];
  const float* encW1 = (const float*)d_in[8];
  const float* encb1 = (const float*)d_in[9];
  const float* encW2 = (const float*)d_in[10];
  const float* encb2 = (const float*)d_in[11];
  const float* encW3 = (const float*)d_in[12];
  const float* encb3 = (const float*)d_in[13];
  const float* decW1 = (const float*)d_in[14];
  const float* decb1 = (const float*)d_in[15];
  const float* decW2 = (const float*)d_in[16];
  const float* decb2 = (const float*)d_in[17];
  const float* decW3 = (const float*)d_in[18];
  const float* decb3 = (const float*)d_in[19];

  int n = in_sizes[0];
  float* acc5 = (float*)d_ws;                  // 5 loss accumulators
  unsigned* counter = (unsigned*)(acc5 + 8);   // ticket
  float* PQ = (float*)(acc5 + 16);             // 256 floats (symp encodes)

  hipMemsetAsync(acc5, 0, 64, stream);         // acc5 + counter

  mlp_main<<<512, 512, 0, stream>>>(
      p0, q0, p1, q1,
      encW1, encb1, encW2, encb2, encW3, encb3,
      decW1, decb1, decW2, decb2, decW3, decb3,
      omega, Pt, Qt, dtp, acc5, counter, PQ, (float*)d_out, n);
}

// Round 3
// 350.948 us; speedup vs baseline: 5.0526x; 5.0526x over previous
//
#include <hip/hip_runtime.h>
#include <stdint.h>
#include <math.h>

// PendulumHJBLoss: 3 MLP passes (2->128->128->2, tanh) over N=524288 + losses.
// R21 = R18 (proven 194us main, 64-VGPR, no-spill) + flipped-MFMA epilogue.
// LESSON (R19/R20 + prior R10-R17): allocator grants these kernels only 64
// arch-VGPRs regardless of launch_bounds/block size; any layout holding more
// live state (direct layer-1, 8-wave variants) spills GBs to scratch. The
// wave-private LDS staging transpose is the register-pressure valve -- KEEP.
// FLIP (verified correct in R19/R20): mfma(Bv, Av) computes C2^T[hidout][elem]
// because the staged frag h1[elem=l15][hid=32s+8q+j] is simultaneously the
// A-frag of h1 and the B-frag of h1^T. Layer-3 partials become lane-local:
// 4-step x16 shfl reduction trees -> 2-step x4 scalars, select chains + SCAT
// machinery deleted, loss tail on quad==0 at natural index e.
// Everything else identical to R18: paired enc over one B-read stream,
// tanh-scale folding (W1/b1/W2/b2 pre-scaled by 2*log2e), fused exact-fp32
// symplectic rows on waves 0..127, ticket-elected finalize.

constexpr float EPS_FD = 1e-4f;
constexpr float K2LOG2E = 2.8853900817779268f;   // 2*log2(e)
constexpr int NBLK = 256;          // 1 block/CU, 16 waves each

typedef float f32x4 __attribute__((ext_vector_type(4)));
typedef short s16x8 __attribute__((ext_vector_type(8)));

// tanh with pre-scaled input: expects x_pre = 2*log2(e) * x
__device__ __forceinline__ float tanh_pre(float x) {
  float e = __builtin_amdgcn_exp2f(x);
  return 1.0f - 2.0f * __builtin_amdgcn_rcpf(e + 1.0f);
}
__device__ __forceinline__ float cos_fast(float x) {
  return __builtin_amdgcn_cosf(x * 0.15915494309189535f);
}
__device__ __forceinline__ unsigned bf16rne(float f) {
  union { float f; unsigned u; } v; v.f = f;
  return (v.u + 0x7FFFu + ((v.u >> 16) & 1u)) >> 16;
}
__device__ __forceinline__ unsigned pack2rne(float a, float b) {
  return bf16rne(a) | (bf16rne(b) << 16);
}
// two fp32 -> packed bf16 pair (round-half-up) with one v_perm
__device__ __forceinline__ unsigned packbf(float lo, float hi) {
  union { float f; unsigned u; } a, b; a.f = lo; b.f = hi;
  return __builtin_amdgcn_perm(b.u + 0x8000u, a.u + 0x8000u, 0x07060302u);
}
// cross-quad reduce (same l15 column): full sum lands on ALL lanes
__device__ __forceinline__ float qred(float v) {
  v += __shfl_xor(v, 16, 64);
  v += __shfl_xor(v, 32, 64);
  return v;
}

// ---------------------------------------------------------------------------
// layer-1 for one 16-elem tile -> h1 frags in regs (via wave-private LDS).
// Staged read gives h1[elem=l15][hid=32s+8q+j] -- serves as B-frag of h1^T
// for the flipped MFMA. Weights/bias pre-scaled by K2LOG2E.
// ---------------------------------------------------------------------------
__device__ __forceinline__ void layer1_frags(
    float pe, float qe, unsigned* hrow,
    float w100, float w101, float w110, float w111, float b10, float b11,
    int lane, int quad, int l15, s16x8 (&A)[4])
{
#pragma unroll
  for (int ee = 0; ee < 16; ee++) {
    float p = __shfl(pe, ee, 64);
    float q = __shfl(qe, ee, 64);
    float a0 = tanh_pre(fmaf(p, w100, fmaf(q, w110, b10)));
    float a1 = tanh_pre(fmaf(p, w101, fmaf(q, w111, b11)));
    hrow[ee * 68 + lane] = packbf(a0, a1);
  }
  __builtin_amdgcn_wave_barrier();   // same-wave LDS ops are in-order
#pragma unroll
  for (int s = 0; s < 4; s++) {
    uint4 u = *reinterpret_cast<const uint4*>(&hrow[l15 * 68 + 16 * s + 4 * quad]);
    A[s] = *reinterpret_cast<s16x8*>(&u);
  }
  __builtin_amdgcn_wave_barrier();   // reads stay before next staging writes
}

// ---------------------------------------------------------------------------
// Dual encoder pass (flipped): C2^T[hidout=16t+4q+r][elem=l15]; layer-3
// accumulates per-lane scalars; cross-quad qred finishes. Outputs valid on
// ALL lanes (elem = l15).
// epi: [0..127]=K*b2[hid]; [128+2*hid]=W3[hid][0]; [128+2*hid+1]=W3[hid][1]
// ---------------------------------------------------------------------------
__device__ __forceinline__ void enc_pair(
    float p0e, float q0e, float p1e, float q1e,
    unsigned* hrow, const uint4* Bf, const float* epi,
    float w100, float w101, float w110, float w111, float b10, float b11,
    int lane, int quad, int l15,
    float& P0v, float& Q0v, float& P1v, float& Q1v)
{
  s16x8 A0[4], A1[4];
  layer1_frags(p0e, q0e, hrow, w100, w101, w110, w111, b10, b11,
               lane, quad, l15, A0);
  layer1_frags(p1e, q1e, hrow, w100, w101, w110, w111, b10, b11,
               lane, quad, l15, A1);

  float sP0 = 0.f, sQ0 = 0.f, sP1 = 0.f, sQ1 = 0.f;
#pragma unroll
  for (int t = 0; t < 8; t++) {
    // acc init = K*b2[16t+4q+r] (row-indexed, b128, 16B-aligned)
    f32x4 acc0 = *reinterpret_cast<const f32x4*>(&epi[16 * t + 4 * quad]);
    f32x4 acc1 = acc0;
#pragma unroll
    for (int s = 0; s < 4; s++) {
      uint4 bu = Bf[(s * 8 + t) * 64 + lane];     // ONE read, TWO MFMAs
      s16x8 Bv = *reinterpret_cast<s16x8*>(&bu);
      // swapped operands: A:=W2-B-frag (= W2^T), B:=h1-frag (= h1^T)
      acc0 = __builtin_amdgcn_mfma_f32_16x16x32_bf16(Bv, A0[s], acc0, 0, 0, 0);
      acc1 = __builtin_amdgcn_mfma_f32_16x16x32_bf16(Bv, A1[s], acc1, 0, 0, 0);
    }
    f32x4 w3a = *reinterpret_cast<const f32x4*>(&epi[128 + 32 * t + 8 * quad]);
    f32x4 w3b = *reinterpret_cast<const f32x4*>(&epi[128 + 32 * t + 8 * quad + 4]);
#pragma unroll
    for (int r = 0; r < 4; r++) {
      float wP = (r == 0) ? w3a[0] : (r == 1) ? w3a[2] : (r == 2) ? w3b[0] : w3b[2];
      float wQ = (r == 0) ? w3a[1] : (r == 1) ? w3a[3] : (r == 2) ? w3b[1] : w3b[3];
      float h0 = tanh_pre(acc0[r]);
      float h1 = tanh_pre(acc1[r]);
      sP0 = fmaf(h0, wP, sP0); sQ0 = fmaf(h0, wQ, sQ0);
      sP1 = fmaf(h1, wP, sP1); sQ1 = fmaf(h1, wQ, sQ1);
    }
  }
  P0v = qred(sP0); Q0v = qred(sQ0);
  P1v = qred(sP1); Q1v = qred(sQ1);
}

// ---------------------------------------------------------------------------
// Single (decoder) pass, flipped. Inputs on owner lanes 0..15 (elem=l15 on
// all lanes after enc, so lane ee holds elem ee -- natural order).
// ---------------------------------------------------------------------------
__device__ __forceinline__ void dec_pass(
    float pe, float qe, unsigned* hrow, const uint4* Bf, const float* epi,
    float w100, float w101, float w110, float w111, float b10, float b11,
    int lane, int quad, int l15, float& vP, float& vQ)
{
  s16x8 A[4];
  layer1_frags(pe, qe, hrow, w100, w101, w110, w111, b10, b11,
               lane, quad, l15, A);
  float sP = 0.f, sQ = 0.f;
#pragma unroll
  for (int t = 0; t < 8; t++) {
    f32x4 acc = *reinterpret_cast<const f32x4*>(&epi[16 * t + 4 * quad]);
#pragma unroll
    for (int s = 0; s < 4; s++) {
      uint4 bu = Bf[(s * 8 + t) * 64 + lane];
      s16x8 Bv = *reinterpret_cast<s16x8*>(&bu);
      acc = __builtin_amdgcn_mfma_f32_16x16x32_bf16(Bv, A[s], acc, 0, 0, 0);
    }
    f32x4 w3a = *reinterpret_cast<const f32x4*>(&epi[128 + 32 * t + 8 * quad]);
    f32x4 w3b = *reinterpret_cast<const f32x4*>(&epi[128 + 32 * t + 8 * quad + 4]);
#pragma unroll
    for (int r = 0; r < 4; r++) {
      float wP = (r == 0) ? w3a[0] : (r == 1) ? w3a[2] : (r == 2) ? w3b[0] : w3b[2];
      float wQ = (r == 0) ? w3a[1] : (r == 1) ? w3a[3] : (r == 2) ? w3b[1] : w3b[3];
      float h = tanh_pre(acc[r]);
      sP = fmaf(h, wP, sP);
      sQ = fmaf(h, wQ, sQ);
    }
  }
  vP = qred(sP); vQ = qred(sQ);
}

// ---------------------------------------------------------------------------
// Main persistent kernel (R18 structure: 1024 thr, 1 block/CU, 16 waves).
// ---------------------------------------------------------------------------
__global__ __launch_bounds__(1024, 1) void mlp_main(
    const float* __restrict__ p0, const float* __restrict__ q0,
    const float* __restrict__ p1, const float* __restrict__ q1,
    const float* __restrict__ eW1, const float* __restrict__ eb1,
    const float* __restrict__ eW2, const float* __restrict__ eb2,
    const float* __restrict__ eW3, const float* __restrict__ eb3,
    const float* __restrict__ dW1, const float* __restrict__ db1,
    const float* __restrict__ dW2, const float* __restrict__ db2,
    const float* __restrict__ dW3, const float* __restrict__ db3,
    const float* __restrict__ omega, const float* __restrict__ Pt,
    const float* __restrict__ Qt, const float* __restrict__ dtp,
    float* __restrict__ acc5, unsigned* __restrict__ counter,
    float* __restrict__ PQ, float* __restrict__ out, int n)
{
  __shared__ uint4 BfE[2048];               // 32 KB enc B-frags (pre-scaled)
  __shared__ uint4 BfD[2048];               // 32 KB dec B-frags (pre-scaled)
  __shared__ unsigned h1s[16][16 * 68 + 4]; // wave-private h1 staging (~70 KB)
  __shared__ __align__(16) float encEpi[384]; // enc K*b2 | W3 interleaved
  __shared__ __align__(16) float decEpi[384]; // dec K*b2 | W3 interleaved
  __shared__ float red[16][5];
  __shared__ unsigned lastflag;

  int tid = threadIdx.x;
  // self-swizzle: frag f=s*8+t; lane L holds B[k=32s+(L>>4)*8+j][col=16t+(L&15)]
  // W2 pre-scaled by K2LOG2E at pack time.
#pragma unroll
  for (int it = 0; it < 8; it++) {
    int id = tid + it * 1024;               // u32 entry 0..8191
    int jj = id & 3, ln = (id >> 2) & 63, f = id >> 8;
    int s = f >> 3, t = f & 7;
    int k   = 32 * s + 8 * (ln >> 4) + 2 * jj;
    int col = 16 * t + (ln & 15);
    ((unsigned*)BfE)[id] = pack2rne(eW2[k * 128 + col] * K2LOG2E,
                                    eW2[(k + 1) * 128 + col] * K2LOG2E);
    ((unsigned*)BfD)[id] = pack2rne(dW2[k * 128 + col] * K2LOG2E,
                                    dW2[(k + 1) * 128 + col] * K2LOG2E);
  }
  if (tid < 128)      encEpi[tid] = eb2[tid] * K2LOG2E;            // K*b2[hid]
  else if (tid < 256) decEpi[tid - 128] = db2[tid - 128] * K2LOG2E;
  else if (tid < 512) encEpi[128 + tid - 256] = eW3[tid - 256];    // raw (128,2)
  else if (tid < 768) decEpi[128 + tid - 512] = dW3[tid - 512];

  int wave = tid >> 6, lane = tid & 63;
  int quad = lane >> 4, l15 = lane & 15;

  // layer-1 consts (lane owns hidden dims 2*lane, 2*lane+1), pre-scaled
  float ew100 = eW1[2 * lane] * K2LOG2E,       ew101 = eW1[2 * lane + 1] * K2LOG2E;
  float ew110 = eW1[128 + 2 * lane] * K2LOG2E, ew111 = eW1[128 + 2 * lane + 1] * K2LOG2E;
  float eb10 = eb1[2 * lane] * K2LOG2E, eb11 = eb1[2 * lane + 1] * K2LOG2E;
  float dw100 = dW1[2 * lane] * K2LOG2E,       dw101 = dW1[2 * lane + 1] * K2LOG2E;
  float dw110 = dW1[128 + 2 * lane] * K2LOG2E, dw111 = dW1[128 + 2 * lane + 1] * K2LOG2E;
  float db10 = db1[2 * lane] * K2LOG2E, db11 = db1[2 * lane + 1] * K2LOG2E;
  float eb3P = eb3[0], eb3Q = eb3[1];
  float db3P = db3[0], db3Q = db3[1];
  float dt = dtp[0];
  float s0 = 0.f, s1 = 0.f, s2 = 0.f, s3 = 0.f, s4 = 0.f;
  __syncthreads();   // LDS staging done; the only block barrier before tail

  int nwaves = gridDim.x * 16;
  int gwave  = blockIdx.x * 16 + wave;
  int ntiles = (n + 15) >> 4;
  unsigned* hrow = &h1s[wave][0];

  // ---- fused exact-fp32 symplectic rows: one per wave for gwave < 128 ----
  // (reads RAW weights from global; unaffected by pre-scaling)
  if (gwave < 128) {
    int r = gwave;
    int m = r & 31, c = r >> 5;           // c: 0=p+e 1=p-e 2=q+e 3=q-e
    float p = p0[m], q = q0[m];
    p += (c == 0) ? EPS_FD : (c == 1) ? -EPS_FD : 0.f;
    q += (c == 2) ? EPS_FD : (c == 3) ? -EPS_FD : 0.f;
    float* hf = (float*)hrow;             // wave-private LDS as fp32 h1[128]
    int t0 = 2 * lane, t1 = 2 * lane + 1;
    float h0 = tanhf(fmaf(p, eW1[t0], fmaf(q, eW1[128 + t0], eb1[t0])));
    float h1v = tanhf(fmaf(p, eW1[t1], fmaf(q, eW1[128 + t1], eb1[t1])));
    hf[t0] = h0; hf[t1] = h1v;
    __builtin_amdgcn_wave_barrier();
    float a0 = eb2[t0], a1 = eb2[t1];
#pragma unroll 8
    for (int k = 0; k < 128; k++) {
      float hk = hf[k];                   // LDS broadcast (same addr all lanes)
      a0 = fmaf(hk, eW2[k * 128 + t0], a0);
      a1 = fmaf(hk, eW2[k * 128 + t1], a1);
    }
    float g0 = tanhf(a0), g1 = tanhf(a1);
    float cP = fmaf(g0, eW3[2 * t0],     g1 * eW3[2 * t1]);
    float cQ = fmaf(g0, eW3[2 * t0 + 1], g1 * eW3[2 * t1 + 1]);
#pragma unroll
    for (int mm = 1; mm < 64; mm <<= 1) {
      cP += __shfl_xor(cP, mm, 64);
      cQ += __shfl_xor(cQ, mm, 64);
    }
    if (lane == 0) {
      atomicExch(&PQ[2 * r],     cP + eb3P);   // device-scope publish
      atomicExch(&PQ[2 * r + 1], cQ + eb3Q);
    }
    __builtin_amdgcn_wave_barrier();      // hf reads done before tile reuse
  }

  for (int tile = gwave; tile < ntiles; tile += nwaves) {
    int base = tile * 16;
    int e = base + l15; if (e >= n) e = n - 1;
    float p0e = p0[e], q0e = q0[e];
    float p1e = p1[e], q1e = q1[e];
    // hoisted loss loads at the natural index (used on quad 0 only)
    float Lom = omega[e], LPt = Pt[e], LQt = Qt[e];

    float P0v, Q0v, P1v, Q1v, RPv, RQv;
    enc_pair(p0e, q0e, p1e, q1e, hrow, BfE, encEpi,
             ew100, ew101, ew110, ew111, eb10, eb11,
             lane, quad, l15, P0v, Q0v, P1v, Q1v);
    P0v += eb3P; Q0v += eb3Q;
    P1v += eb3P; Q1v += eb3Q;
    // dec input: enc outputs at elem=l15 on all lanes (owner lanes 0..15)
    dec_pass(P0v, Q0v, hrow, BfD, decEpi,
             dw100, dw101, dw110, dw111, db10, db11,
             lane, quad, l15, RPv, RQv);
    RPv += db3P; RQv += db3Q;

    if (quad == 0 && base + l15 < n) {
      float dp = p0e - RPv, dq = q0e - RQv;
      s0 += dp * dp + dq * dq;                       // recon
      float d1 = P0v - P1v; s1 += d1 * d1;           // conservation
      s2 += 1.0f - cos_fast(Q1v - Q0v - Lom * dt);   // evolution
      float g = P0v - LPt; s3 += g * g;              // gauge P
      s4 += 1.0f - cos_fast(Q0v - LQt);              // gauge Q
    }
  }

  // block reduction -> global atomics -> ticket -> last block finalizes
#pragma unroll
  for (int m = 1; m < 64; m <<= 1) {
    s0 += __shfl_xor(s0, m, 64);
    s1 += __shfl_xor(s1, m, 64);
    s2 += __shfl_xor(s2, m, 64);
    s3 += __shfl_xor(s3, m, 64);
    s4 += __shfl_xor(s4, m, 64);
  }
  if (lane == 0) {
    red[wave][0] = s0; red[wave][1] = s1; red[wave][2] = s2;
    red[wave][3] = s3; red[wave][4] = s4;
  }
  __syncthreads();
  if (tid == 0) {
#pragma unroll
    for (int i = 0; i < 5; i++) {
      float v = 0.f;
#pragma unroll
      for (int w = 0; w < 16; w++) v += red[w][i];
      atomicAdd(&acc5[i], v);
    }
    __threadfence();
    unsigned prev = atomicAdd(counter, 1u);
    lastflag = (prev == gridDim.x - 1) ? 1u : 0u;
  }
  __syncthreads();
  if (lastflag) {
    __threadfence();
    if (tid < 64) {
      float v = 0.f;
      if (tid < 32) {
        // PQ read through device-scope atomics (cross-XCD safe)
        float Ppp = atomicAdd(&PQ[2 * tid], 0.f);
        float Qpp = atomicAdd(&PQ[2 * tid + 1], 0.f);
        float Ppm = atomicAdd(&PQ[2 * (32 + tid)], 0.f);
        float Qpm = atomicAdd(&PQ[2 * (32 + tid) + 1], 0.f);
        float Pqp = atomicAdd(&PQ[2 * (64 + tid)], 0.f);
        float Qqp = atomicAdd(&PQ[2 * (64 + tid) + 1], 0.f);
        float Pqm = atomicAdd(&PQ[2 * (96 + tid)], 0.f);
        float Qqm = atomicAdd(&PQ[2 * (96 + tid) + 1], 0.f);
        float inv2e = 1.0f / (2.0f * EPS_FD);
        float dPdp = (Ppp - Ppm) * inv2e, dPdq = (Pqp - Pqm) * inv2e;
        float dQdp = (Qpp - Qpm) * inv2e, dQdq = (Qqp - Qqm) * inv2e;
        float pb = dPdq * dQdp - dPdp * dQdq;
        float d = fabsf(pb) - 1.0f;
        v = d * d;
      }
#pragma unroll
      for (int m = 1; m < 64; m <<= 1) v += __shfl_xor(v, m, 64);
      if (tid == 0) {
        float inv_n = 1.0f / (float)n;
        float recon = atomicAdd(&acc5[0], 0.f) * inv_n;
        float cons  = atomicAdd(&acc5[1], 0.f) * inv_n;
        float evo   = atomicAdd(&acc5[2], 0.f) * inv_n;
        float gauge = (atomicAdd(&acc5[3], 0.f) + atomicAdd(&acc5[4], 0.f)) * inv_n;
        float symp  = v * (1.0f / 32.0f);
        float total = recon + 10.0f * cons + 5.0f * evo + 0.1f * symp + 5.0f * gauge;
        out[0] = total; out[1] = recon; out[2] = cons;
        out[3] = evo;   out[4] = symp;  out[5] = gauge;
      }
    }
  }
}

extern "C" void kernel_launch(void* const* d_in, const int* in_sizes, int n_in,
                              void* d_out, int out_size, void* d_ws, size_t ws_size,
                              hipStream_t stream)
{
  const float* p0    = (const float*)d_in[0];
  const float* q0    = (const float*)d_in[1];
  const float* p1    = (const float*)d_in[2];
  const float* q1    = (const float*)d_in[3];
  const float* omega = (const float*)d_in[4];
  const float* dtp   = (const float*)d_in[5];
  const float* Pt    = (const float*)d_in[6];
  const float* Qt    = (const float*)d_in[7];
  const float* encW1 = (const float*)d_in[8];
  const float* encb1 = (const float*)d_in[9];
  const float* encW2 = (const float*)d_in[10];
  const float* encb2 = (const float*)d_in[11];
  const float* encW3 = (const float*)d_in[12];
  const float* encb3 = (const float*)d_in[13];
  const float* decW1 = (const float*)d_in[14];
  const float* decb1 = (const float*)d_in[15];
  const float* decW2 = (const float*)d_in[16];
  const float* decb2 = (const float*)d_in[17];
  const float* decW3 = (const float*)d_in[18];
  const float* decb3 = (const float*)d_in[19];

  int n = in_sizes[0];
  float* acc5 = (float*)d_ws;                  // 5 loss accumulators
  unsigned* counter = (unsigned*)(acc5 + 8);   // ticket
  float* PQ = (float*)(acc5 + 16);             // 256 floats (symp encodes)

  hipMemsetAsync(acc5, 0, 64, stream);         // acc5 + counter

  mlp_main<<<NBLK, 1024, 0, stream>>>(
      p0, q0, p1, q1,
      encW1, encb1, encW2, encb2, encW3, encb3,
      decW1, decb1, decW2, decb2, decW3, decb3,
      omega, Pt, Qt, dtp, acc5, counter, PQ, (float*)d_out, n);
}

// Round 4
// 256.692 us; speedup vs baseline: 6.9078x; 1.3672x over previous
//
#include <hip/hip_runtime.h>
#include <stdint.h>
#include <math.h>

// PendulumHJBLoss: 3 MLP passes (2->128->128->2, tanh) over N=524288 + losses.
// R22 = R18 structure + flipped-MFMA epilogue at SCALAR load granularity.
// LESSON LEDGER:
//  - R10-R17, R19, R20: any layout holding >64 live VGPRs spills GBs (the
//    allocator caps these kernels at 64 arch VGPRs). Wave-private LDS staging
//    transpose is the pressure valve -- KEEP.
//  - R21: flip correct (absmax 0) but f32x4 epilogue loads (12 wide regs/iter,
//    96 floats across the unrolled t-loop) re-spilled (~0.8GB scratch).
//  - R22 fix: acc init = zeros (b2 added post-MFMA inside tanh arg), w3 via
//    scalar float2 per r -- 3 transient floats at a time, R18's granularity.
// Flip recap: mfma(Bv, Av) computes C2^T[hidout=16t+4q+r][elem=l15] (staged
// frag h1[elem=l15][hid=32s+8q+j] is simultaneously A-frag of h1 and B-frag
// of h1^T). Layer-3 partials lane-local: 2-step qred replaces 4-step x16
// shfl trees; SCAT machinery and select chains deleted.

constexpr float EPS_FD = 1e-4f;
constexpr float K2LOG2E = 2.8853900817779268f;   // 2*log2(e)
constexpr int NBLK = 256;          // 1 block/CU, 16 waves each

typedef float f32x4 __attribute__((ext_vector_type(4)));
typedef short s16x8 __attribute__((ext_vector_type(8)));

// tanh with pre-scaled input: expects x_pre = 2*log2(e) * x
__device__ __forceinline__ float tanh_pre(float x) {
  float e = __builtin_amdgcn_exp2f(x);
  return 1.0f - 2.0f * __builtin_amdgcn_rcpf(e + 1.0f);
}
__device__ __forceinline__ float cos_fast(float x) {
  return __builtin_amdgcn_cosf(x * 0.15915494309189535f);
}
__device__ __forceinline__ unsigned bf16rne(float f) {
  union { float f; unsigned u; } v; v.f = f;
  return (v.u + 0x7FFFu + ((v.u >> 16) & 1u)) >> 16;
}
__device__ __forceinline__ unsigned pack2rne(float a, float b) {
  return bf16rne(a) | (bf16rne(b) << 16);
}
// two fp32 -> packed bf16 pair (round-half-up) with one v_perm
__device__ __forceinline__ unsigned packbf(float lo, float hi) {
  union { float f; unsigned u; } a, b; a.f = lo; b.f = hi;
  return __builtin_amdgcn_perm(b.u + 0x8000u, a.u + 0x8000u, 0x07060302u);
}
// cross-quad reduce (same l15 column): full sum lands on ALL lanes
__device__ __forceinline__ float qred(float v) {
  v += __shfl_xor(v, 16, 64);
  v += __shfl_xor(v, 32, 64);
  return v;
}

// ---------------------------------------------------------------------------
// layer-1 for one 16-elem tile -> h1 frags in regs (via wave-private LDS).
// Staged read gives h1[elem=l15][hid=32s+8q+j] -- serves as B-frag of h1^T
// for the flipped MFMA. Weights/bias pre-scaled by K2LOG2E.
// ---------------------------------------------------------------------------
__device__ __forceinline__ void layer1_frags(
    float pe, float qe, unsigned* hrow,
    float w100, float w101, float w110, float w111, float b10, float b11,
    int lane, int quad, int l15, s16x8 (&A)[4])
{
#pragma unroll
  for (int ee = 0; ee < 16; ee++) {
    float p = __shfl(pe, ee, 64);
    float q = __shfl(qe, ee, 64);
    float a0 = tanh_pre(fmaf(p, w100, fmaf(q, w110, b10)));
    float a1 = tanh_pre(fmaf(p, w101, fmaf(q, w111, b11)));
    hrow[ee * 68 + lane] = packbf(a0, a1);
  }
  __builtin_amdgcn_wave_barrier();   // same-wave LDS ops are in-order
#pragma unroll
  for (int s = 0; s < 4; s++) {
    uint4 u = *reinterpret_cast<const uint4*>(&hrow[l15 * 68 + 16 * s + 4 * quad]);
    A[s] = *reinterpret_cast<s16x8*>(&u);
  }
  __builtin_amdgcn_wave_barrier();   // reads stay before next staging writes
}

// ---------------------------------------------------------------------------
// Dual encoder pass (flipped): C2^T[hidout=16t+4q+r][elem=l15]; layer-3
// accumulates per-lane scalars; cross-quad qred finishes. Outputs valid on
// ALL lanes (elem = l15).
// epi: [0..127]=K*b2[hid]; [128+2*hid]=W3[hid][0]; [128+2*hid+1]=W3[hid][1]
// ---------------------------------------------------------------------------
__device__ __forceinline__ void enc_pair(
    float p0e, float q0e, float p1e, float q1e,
    unsigned* hrow, const uint4* Bf, const float* epi,
    float w100, float w101, float w110, float w111, float b10, float b11,
    int lane, int quad, int l15,
    float& P0v, float& Q0v, float& P1v, float& Q1v)
{
  s16x8 A0[4], A1[4];
  layer1_frags(p0e, q0e, hrow, w100, w101, w110, w111, b10, b11,
               lane, quad, l15, A0);
  layer1_frags(p1e, q1e, hrow, w100, w101, w110, w111, b10, b11,
               lane, quad, l15, A1);

  float sP0 = 0.f, sQ0 = 0.f, sP1 = 0.f, sQ1 = 0.f;
#pragma unroll
  for (int t = 0; t < 8; t++) {
    f32x4 acc0 = {0.f, 0.f, 0.f, 0.f};     // b2 folded in post-MFMA
    f32x4 acc1 = {0.f, 0.f, 0.f, 0.f};
#pragma unroll
    for (int s = 0; s < 4; s++) {
      uint4 bu = Bf[(s * 8 + t) * 64 + lane];     // ONE read, TWO MFMAs
      s16x8 Bv = *reinterpret_cast<s16x8*>(&bu);
      // swapped operands: A:=W2-B-frag (= W2^T), B:=h1-frag (= h1^T)
      acc0 = __builtin_amdgcn_mfma_f32_16x16x32_bf16(Bv, A0[s], acc0, 0, 0, 0);
      acc1 = __builtin_amdgcn_mfma_f32_16x16x32_bf16(Bv, A1[s], acc1, 0, 0, 0);
    }
#pragma unroll
    for (int r = 0; r < 4; r++) {
      int hid = 16 * t + 4 * quad + r;
      float kb2 = epi[hid];                                        // scalar
      float2 w3 = *reinterpret_cast<const float2*>(&epi[128 + 2 * hid]);
      float h0 = tanh_pre(acc0[r] + kb2);
      float h1 = tanh_pre(acc1[r] + kb2);
      sP0 = fmaf(h0, w3.x, sP0); sQ0 = fmaf(h0, w3.y, sQ0);
      sP1 = fmaf(h1, w3.x, sP1); sQ1 = fmaf(h1, w3.y, sQ1);
    }
  }
  P0v = qred(sP0); Q0v = qred(sQ0);
  P1v = qred(sP1); Q1v = qred(sQ1);
}

// ---------------------------------------------------------------------------
// Single (decoder) pass, flipped. Inputs at elem=l15 on all lanes.
// ---------------------------------------------------------------------------
__device__ __forceinline__ void dec_pass(
    float pe, float qe, unsigned* hrow, const uint4* Bf, const float* epi,
    float w100, float w101, float w110, float w111, float b10, float b11,
    int lane, int quad, int l15, float& vP, float& vQ)
{
  s16x8 A[4];
  layer1_frags(pe, qe, hrow, w100, w101, w110, w111, b10, b11,
               lane, quad, l15, A);
  float sP = 0.f, sQ = 0.f;
#pragma unroll
  for (int t = 0; t < 8; t++) {
    f32x4 acc = {0.f, 0.f, 0.f, 0.f};
#pragma unroll
    for (int s = 0; s < 4; s++) {
      uint4 bu = Bf[(s * 8 + t) * 64 + lane];
      s16x8 Bv = *reinterpret_cast<s16x8*>(&bu);
      acc = __builtin_amdgcn_mfma_f32_16x16x32_bf16(Bv, A[s], acc, 0, 0, 0);
    }
#pragma unroll
    for (int r = 0; r < 4; r++) {
      int hid = 16 * t + 4 * quad + r;
      float kb2 = epi[hid];
      float2 w3 = *reinterpret_cast<const float2*>(&epi[128 + 2 * hid]);
      float h = tanh_pre(acc[r] + kb2);
      sP = fmaf(h, w3.x, sP);
      sQ = fmaf(h, w3.y, sQ);
    }
  }
  vP = qred(sP); vQ = qred(sQ);
}

// ---------------------------------------------------------------------------
// Main persistent kernel (R18 structure: 1024 thr, 1 block/CU, 16 waves).
// ---------------------------------------------------------------------------
__global__ __launch_bounds__(1024, 1) void mlp_main(
    const float* __restrict__ p0, const float* __restrict__ q0,
    const float* __restrict__ p1, const float* __restrict__ q1,
    const float* __restrict__ eW1, const float* __restrict__ eb1,
    const float* __restrict__ eW2, const float* __restrict__ eb2,
    const float* __restrict__ eW3, const float* __restrict__ eb3,
    const float* __restrict__ dW1, const float* __restrict__ db1,
    const float* __restrict__ dW2, const float* __restrict__ db2,
    const float* __restrict__ dW3, const float* __restrict__ db3,
    const float* __restrict__ omega, const float* __restrict__ Pt,
    const float* __restrict__ Qt, const float* __restrict__ dtp,
    float* __restrict__ acc5, unsigned* __restrict__ counter,
    float* __restrict__ PQ, float* __restrict__ out, int n)
{
  __shared__ uint4 BfE[2048];               // 32 KB enc B-frags (pre-scaled)
  __shared__ uint4 BfD[2048];               // 32 KB dec B-frags (pre-scaled)
  __shared__ unsigned h1s[16][16 * 68 + 4]; // wave-private h1 staging (~70 KB)
  __shared__ __align__(16) float encEpi[384]; // enc K*b2 | W3 interleaved
  __shared__ __align__(16) float decEpi[384]; // dec K*b2 | W3 interleaved
  __shared__ float red[16][5];
  __shared__ unsigned lastflag;

  int tid = threadIdx.x;
  // self-swizzle: frag f=s*8+t; lane L holds B[k=32s+(L>>4)*8+j][col=16t+(L&15)]
  // W2 pre-scaled by K2LOG2E at pack time.
#pragma unroll
  for (int it = 0; it < 8; it++) {
    int id = tid + it * 1024;               // u32 entry 0..8191
    int jj = id & 3, ln = (id >> 2) & 63, f = id >> 8;
    int s = f >> 3, t = f & 7;
    int k   = 32 * s + 8 * (ln >> 4) + 2 * jj;
    int col = 16 * t + (ln & 15);
    ((unsigned*)BfE)[id] = pack2rne(eW2[k * 128 + col] * K2LOG2E,
                                    eW2[(k + 1) * 128 + col] * K2LOG2E);
    ((unsigned*)BfD)[id] = pack2rne(dW2[k * 128 + col] * K2LOG2E,
                                    dW2[(k + 1) * 128 + col] * K2LOG2E);
  }
  if (tid < 128)      encEpi[tid] = eb2[tid] * K2LOG2E;            // K*b2[hid]
  else if (tid < 256) decEpi[tid - 128] = db2[tid - 128] * K2LOG2E;
  else if (tid < 512) encEpi[128 + tid - 256] = eW3[tid - 256];    // raw (128,2)
  else if (tid < 768) decEpi[128 + tid - 512] = dW3[tid - 512];

  int wave = tid >> 6, lane = tid & 63;
  int quad = lane >> 4, l15 = lane & 15;

  // layer-1 consts (lane owns hidden dims 2*lane, 2*lane+1), pre-scaled
  float ew100 = eW1[2 * lane] * K2LOG2E,       ew101 = eW1[2 * lane + 1] * K2LOG2E;
  float ew110 = eW1[128 + 2 * lane] * K2LOG2E, ew111 = eW1[128 + 2 * lane + 1] * K2LOG2E;
  float eb10 = eb1[2 * lane] * K2LOG2E, eb11 = eb1[2 * lane + 1] * K2LOG2E;
  float dw100 = dW1[2 * lane] * K2LOG2E,       dw101 = dW1[2 * lane + 1] * K2LOG2E;
  float dw110 = dW1[128 + 2 * lane] * K2LOG2E, dw111 = dW1[128 + 2 * lane + 1] * K2LOG2E;
  float db10 = db1[2 * lane] * K2LOG2E, db11 = db1[2 * lane + 1] * K2LOG2E;
  float eb3P = eb3[0], eb3Q = eb3[1];
  float db3P = db3[0], db3Q = db3[1];
  float dt = dtp[0];
  float s0 = 0.f, s1 = 0.f, s2 = 0.f, s3 = 0.f, s4 = 0.f;
  __syncthreads();   // LDS staging done; the only block barrier before tail

  int nwaves = gridDim.x * 16;
  int gwave  = blockIdx.x * 16 + wave;
  int ntiles = (n + 15) >> 4;
  unsigned* hrow = &h1s[wave][0];

  // ---- fused exact-fp32 symplectic rows: one per wave for gwave < 128 ----
  // (reads RAW weights from global; unaffected by pre-scaling)
  if (gwave < 128) {
    int r = gwave;
    int m = r & 31, c = r >> 5;           // c: 0=p+e 1=p-e 2=q+e 3=q-e
    float p = p0[m], q = q0[m];
    p += (c == 0) ? EPS_FD : (c == 1) ? -EPS_FD : 0.f;
    q += (c == 2) ? EPS_FD : (c == 3) ? -EPS_FD : 0.f;
    float* hf = (float*)hrow;             // wave-private LDS as fp32 h1[128]
    int t0 = 2 * lane, t1 = 2 * lane + 1;
    float h0 = tanhf(fmaf(p, eW1[t0], fmaf(q, eW1[128 + t0], eb1[t0])));
    float h1v = tanhf(fmaf(p, eW1[t1], fmaf(q, eW1[128 + t1], eb1[t1])));
    hf[t0] = h0; hf[t1] = h1v;
    __builtin_amdgcn_wave_barrier();
    float a0 = eb2[t0], a1 = eb2[t1];
#pragma unroll 8
    for (int k = 0; k < 128; k++) {
      float hk = hf[k];                   // LDS broadcast (same addr all lanes)
      a0 = fmaf(hk, eW2[k * 128 + t0], a0);
      a1 = fmaf(hk, eW2[k * 128 + t1], a1);
    }
    float g0 = tanhf(a0), g1 = tanhf(a1);
    float cP = fmaf(g0, eW3[2 * t0],     g1 * eW3[2 * t1]);
    float cQ = fmaf(g0, eW3[2 * t0 + 1], g1 * eW3[2 * t1 + 1]);
#pragma unroll
    for (int mm = 1; mm < 64; mm <<= 1) {
      cP += __shfl_xor(cP, mm, 64);
      cQ += __shfl_xor(cQ, mm, 64);
    }
    if (lane == 0) {
      atomicExch(&PQ[2 * r],     cP + eb3P);   // device-scope publish
      atomicExch(&PQ[2 * r + 1], cQ + eb3Q);
    }
    __builtin_amdgcn_wave_barrier();      // hf reads done before tile reuse
  }

  for (int tile = gwave; tile < ntiles; tile += nwaves) {
    int base = tile * 16;
    int e = base + l15; if (e >= n) e = n - 1;
    float p0e = p0[e], q0e = q0[e];
    float p1e = p1[e], q1e = q1[e];
    // hoisted loss loads at the natural index (used on quad 0 only)
    float Lom = omega[e], LPt = Pt[e], LQt = Qt[e];

    float P0v, Q0v, P1v, Q1v, RPv, RQv;
    enc_pair(p0e, q0e, p1e, q1e, hrow, BfE, encEpi,
             ew100, ew101, ew110, ew111, eb10, eb11,
             lane, quad, l15, P0v, Q0v, P1v, Q1v);
    P0v += eb3P; Q0v += eb3Q;
    P1v += eb3P; Q1v += eb3Q;
    // dec input: enc outputs at elem=l15 on all lanes
    dec_pass(P0v, Q0v, hrow, BfD, decEpi,
             dw100, dw101, dw110, dw111, db10, db11,
             lane, quad, l15, RPv, RQv);
    RPv += db3P; RQv += db3Q;

    if (quad == 0 && base + l15 < n) {
      float dp = p0e - RPv, dq = q0e - RQv;
      s0 += dp * dp + dq * dq;                       // recon
      float d1 = P0v - P1v; s1 += d1 * d1;           // conservation
      s2 += 1.0f - cos_fast(Q1v - Q0v - Lom * dt);   // evolution
      float g = P0v - LPt; s3 += g * g;              // gauge P
      s4 += 1.0f - cos_fast(Q0v - LQt);              // gauge Q
    }
  }

  // block reduction -> global atomics -> ticket -> last block finalizes
#pragma unroll
  for (int m = 1; m < 64; m <<= 1) {
    s0 += __shfl_xor(s0, m, 64);
    s1 += __shfl_xor(s1, m, 64);
    s2 += __shfl_xor(s2, m, 64);
    s3 += __shfl_xor(s3, m, 64);
    s4 += __shfl_xor(s4, m, 64);
  }
  if (lane == 0) {
    red[wave][0] = s0; red[wave][1] = s1; red[wave][2] = s2;
    red[wave][3] = s3; red[wave][4] = s4;
  }
  __syncthreads();
  if (tid == 0) {
#pragma unroll
    for (int i = 0; i < 5; i++) {
      float v = 0.f;
#pragma unroll
      for (int w = 0; w < 16; w++) v += red[w][i];
      atomicAdd(&acc5[i], v);
    }
    __threadfence();
    unsigned prev = atomicAdd(counter, 1u);
    lastflag = (prev == gridDim.x - 1) ? 1u : 0u;
  }
  __syncthreads();
  if (lastflag) {
    __threadfence();
    if (tid < 64) {
      float v = 0.f;
      if (tid < 32) {
        // PQ read through device-scope atomics (cross-XCD safe)
        float Ppp = atomicAdd(&PQ[2 * tid], 0.f);
        float Qpp = atomicAdd(&PQ[2 * tid + 1], 0.f);
        float Ppm = atomicAdd(&PQ[2 * (32 + tid)], 0.f);
        float Qpm = atomicAdd(&PQ[2 * (32 + tid) + 1], 0.f);
        float Pqp = atomicAdd(&PQ[2 * (64 + tid)], 0.f);
        float Qqp = atomicAdd(&PQ[2 * (64 + tid) + 1], 0.f);
        float Pqm = atomicAdd(&PQ[2 * (96 + tid)], 0.f);
        float Qqm = atomicAdd(&PQ[2 * (96 + tid) + 1], 0.f);
        float inv2e = 1.0f / (2.0f * EPS_FD);
        float dPdp = (Ppp - Ppm) * inv2e, dPdq = (Pqp - Pqm) * inv2e;
        float dQdp = (Qpp - Qpm) * inv2e, dQdq = (Qqp - Qqm) * inv2e;
        float pb = dPdq * dQdp - dPdp * dQdq;
        float d = fabsf(pb) - 1.0f;
        v = d * d;
      }
#pragma unroll
      for (int m = 1; m < 64; m <<= 1) v += __shfl_xor(v, m, 64);
      if (tid == 0) {
        float inv_n = 1.0f / (float)n;
        float recon = atomicAdd(&acc5[0], 0.f) * inv_n;
        float cons  = atomicAdd(&acc5[1], 0.f) * inv_n;
        float evo   = atomicAdd(&acc5[2], 0.f) * inv_n;
        float gauge = (atomicAdd(&acc5[3], 0.f) + atomicAdd(&acc5[4], 0.f)) * inv_n;
        float symp  = v * (1.0f / 32.0f);
        float total = recon + 10.0f * cons + 5.0f * evo + 0.1f * symp + 5.0f * gauge;
        out[0] = total; out[1] = recon; out[2] = cons;
        out[3] = evo;   out[4] = symp;  out[5] = gauge;
      }
    }
  }
}

extern "C" void kernel_launch(void* const* d_in, const int* in_sizes, int n_in,
                              void* d_out, int out_size, void* d_ws, size_t ws_size,
                              hipStream_t stream)
{
  const float* p0    = (const float*)d_in[0];
  const float* q0    = (const float*)d_in[1];
  const float* p1    = (const float*)d_in[2];
  const float* q1    = (const float*)d_in[3];
  const float* omega = (const float*)d_in[4];
  const float* dtp   = (const float*)d_in[5];
  const float* Pt    = (const float*)d_in[6];
  const float* Qt    = (const float*)d_in[7];
  const float* encW1 = (const float*)d_in[8];
  const float* encb1 = (const float*)d_in[9];
  const float* encW2 = (const float*)d_in[10];
  const float* encb2 = (const float*)d_in[11];
  const float* encW3 = (const float*)d_in[12];
  const float* encb3 = (const float*)d_in[13];
  const float* decW1 = (const float*)d_in[14];
  const float* decb1 = (const float*)d_in[15];
  const float* decW2 = (const float*)d_in[16];
  const float* decb2 = (const float*)d_in[17];
  const float* decW3 = (const float*)d_in[18];
  const float* decb3 = (const float*)d_in[19];

  int n = in_sizes[0];
  float* acc5 = (float*)d_ws;                  // 5 loss accumulators
  unsigned* counter = (unsigned*)(acc5 + 8);   // ticket
  float* PQ = (float*)(acc5 + 16);             // 256 floats (symp encodes)

  hipMemsetAsync(acc5, 0, 64, stream);         // acc5 + counter

  mlp_main<<<NBLK, 1024, 0, stream>>>(
      p0, q0, p1, q1,
      encW1, encb1, encW2, encb2, encW3, encb3,
      decW1, decb1, decW2, decb2, decW3, decb3,
      omega, Pt, Qt, dtp, acc5, counter, PQ, (float*)d_out, n);
}